// Round 6
// baseline (456.652 us; speedup 1.0000x reference)
//
#include <hip/hip_runtime.h>

#define NNODES 50000
#define DIM 512
#define HID 128
#define NCLS 32
#define NBINS 196          // ceil(50000 / 256), bin = dst >> 8
#define CHUNK 8192         // edges per block in hist/scatter passes
#define AGG_WAVES_G1 4096
#define AGG_WAVES_G2 8192
#define A3_WAVES 4096
#define HS_SCALE 64.0f
#define HS_ISCALE 0.015625f
#define CHSZ ((size_t)NNODES * 64)   // bytes per hs8 chunk (3.2 MB, < 4MiB L2)

typedef __attribute__((ext_vector_type(8))) short bf16x8;
typedef __attribute__((ext_vector_type(4))) float f32x4;
typedef __attribute__((ext_vector_type(2))) float f32x2;

__device__ __forceinline__ unsigned short f2bf(float f) {
    union { float f; unsigned int u; } a; a.f = f;
    unsigned int u = a.u;
    u += 0x7fff + ((u >> 16) & 1);   // round-to-nearest-even
    return (unsigned short)(u >> 16);
}
__device__ __forceinline__ float bf2f(unsigned short h) {
    union { unsigned int u; float f; } a; a.u = ((unsigned int)h) << 16;
    return a.f;
}
// f32 -> fp8 e4m3 (OCP on gfx950), RNE
__device__ __forceinline__ unsigned char f2fp8(float f) {
    int p = __builtin_amdgcn_cvt_pk_fp8_f32(f, 0.f, 0, false);
    return (unsigned char)(p & 0xff);
}
// 4 packed fp8 -> two f32x2 accumulators (v_pk_add_f32)
__device__ __forceinline__ void fp8add2(unsigned int u, f32x2& a01, f32x2& a23) {
    a01 += __builtin_amdgcn_cvt_pk_f32_fp8((int)u, false);
    a23 += __builtin_amdgcn_cvt_pk_f32_fp8((int)u, true);
}
// min v in [0,NNODES] with rp[v] >= q
__device__ __forceinline__ int lbound(const int* __restrict__ rp, int q) {
    int lo = 0, hi = NNODES;
    while (lo < hi) { int mid = (lo + hi) >> 1; if (rp[mid] >= q) hi = mid; else lo = mid + 1; }
    return lo;
}

// ============ deterministic CSR build: counting sort by dst ============

__global__ __launch_bounds__(256)
void hist_kernel(const int* __restrict__ dst, int E, int nb, int* __restrict__ hist) {
    __shared__ int h[NBINS];
    int tid = threadIdx.x;
    for (int i = tid; i < NBINS; i += 256) h[i] = 0;
    __syncthreads();
    int e0 = blockIdx.x * CHUNK;
    int e1 = min(E, e0 + CHUNK);
    for (int e = e0 + tid; e < e1; e += 256)
        atomicAdd(&h[dst[e] >> 8], 1);
    __syncthreads();
    for (int i = tid; i < NBINS; i += 256)
        hist[(size_t)i * nb + blockIdx.x] = h[i];
}

__global__ __launch_bounds__(256)
void scan_row_kernel(int* __restrict__ data, int n, int* __restrict__ total) {
    int* row = data + (size_t)blockIdx.x * n;
    __shared__ int wsum[4];
    int tid = threadIdx.x, lane = tid & 63, wid = tid >> 6;
    int base = 0;
    for (int start = 0; start < n; start += 256) {
        int i = start + tid;
        int v = (i < n) ? row[i] : 0;
        int x = v;
        #pragma unroll
        for (int off = 1; off < 64; off <<= 1) {
            int t = __shfl_up(x, off);
            if (lane >= off) x += t;
        }
        if (lane == 63) wsum[wid] = x;
        __syncthreads();
        int woff = 0, tot = 0;
        #pragma unroll
        for (int w = 0; w < 4; ++w) { int s = wsum[w]; if (w < wid) woff += s; tot += s; }
        __syncthreads();
        if (i < n) row[i] = base + woff + x - v;
        base += tot;
    }
    if (tid == 0) total[blockIdx.x] = base;
}

__global__ __launch_bounds__(256)
void scatter_kernel(const int* __restrict__ src, const int* __restrict__ dst, int E, int nb,
                    const int* __restrict__ hist, const int* __restrict__ binStart,
                    unsigned int* __restrict__ binned) {
    __shared__ int cur[NBINS];
    int tid = threadIdx.x;
    for (int i = tid; i < NBINS; i += 256)
        cur[i] = hist[(size_t)i * nb + blockIdx.x] + binStart[i];
    __syncthreads();
    int e0 = blockIdx.x * CHUNK;
    int e1 = min(E, e0 + CHUNK);
    for (int e = e0 + tid; e < e1; e += 256) {
        int d = dst[e];
        int b = d >> 8;
        int p = atomicAdd(&cur[b], 1);   // LDS atomic only
        binned[p] = ((unsigned int)(d & 255) << 16) | (unsigned int)src[e];
    }
}

__global__ __launch_bounds__(256)
void binfill_kernel(const unsigned int* __restrict__ binned, const int* __restrict__ binStart,
                    int* __restrict__ rowptr, float* __restrict__ dinv, int* __restrict__ col,
                    int totalE) {
    __shared__ int cnt[256], cur[256];
    __shared__ int wsum[4];
    int b = blockIdx.x;
    int tid = threadIdx.x, lane = tid & 63, wid = tid >> 6;
    int s = binStart[b], e = binStart[b + 1];
    cnt[tid] = 0;
    __syncthreads();
    for (int i = s + tid; i < e; i += 256)
        atomicAdd(&cnt[binned[i] >> 16], 1);
    __syncthreads();
    int v = cnt[tid];
    int x = v;
    #pragma unroll
    for (int off = 1; off < 64; off <<= 1) {
        int t = __shfl_up(x, off);
        if (lane >= off) x += t;
    }
    if (lane == 63) wsum[wid] = x;
    __syncthreads();
    int woff = 0;
    #pragma unroll
    for (int w = 0; w < 4; ++w) if (w < wid) woff += wsum[w];
    int ex = woff + x - v;               // exclusive prefix within bin
    cur[tid] = ex;
    __syncthreads();
    int node = b * 256 + tid;
    if (node < NNODES) {
        rowptr[node] = s + ex;
        dinv[node] = rsqrtf((float)v + 1.0f);   // +1 self-loop
    }
    if (b == 0 && tid == 0) rowptr[NNODES] = totalE;
    for (int i = s + tid; i < e; i += 256) {
        unsigned int pk = binned[i];
        int ld = pk >> 16;
        int p = atomicAdd(&cur[ld], 1);  // LDS atomic only
        col[s + p] = (int)(pk & 0xffff);
    }
}

// ---- W transpose+cast: Wt[c][k] bf16, c in [0,256): c<128 -> W1 col, else W2 col ----

__global__ __launch_bounds__(256)
void convW_kernel(const float* __restrict__ W1, const float* __restrict__ W2,
                  unsigned short* __restrict__ Wt) {
    int k = blockIdx.x;          // 0..511
    int c = threadIdx.x;         // 0..255
    float v = (c < HID) ? W1[(size_t)k * HID + c] : W2[(size_t)k * HID + (c - HID)];
    Wt[(size_t)c * DIM + k] = f2bf(v);
}

// ---- MFMA GEMM: hs8 chunk-major [chunk][node][64]: chunk=wave, fp8(64*dinv*(x@W)) ----

__global__ __launch_bounds__(256)
void gemm12_mfma_kernel(const float* __restrict__ x, const unsigned short* __restrict__ Wt,
                        const float* __restrict__ dinv1, const float* __restrict__ dinv2,
                        unsigned char* __restrict__ hs8) {
    __shared__ unsigned short As[64 * 40];    // 64 rows, pitch 40 bf16
    __shared__ unsigned short Bs[256 * 40];   // 256 cols, pitch 40 bf16
    int tid = threadIdx.x;
    int m0 = blockIdx.x * 64;

    int wv = tid >> 6;           // wave 0..3 == chunk id
    int l  = tid & 63;
    int lr = l & 15;             // fragment row/col
    int lg = l >> 4;             // k-granule 0..3

    int ar = tid >> 2;           // A row 0..63
    int ag = tid & 3;            // A k-granule
    int bc = tid >> 2;           // B col 0..63 (+64*i)
    int bg = tid & 3;            // B k-granule

    bool arow_ok = (m0 + ar) < NNODES;
    const float* xrow = x + (size_t)(m0 + ar) * DIM;

    f32x4 acc[4][4];
    #pragma unroll
    for (int m = 0; m < 4; ++m)
        #pragma unroll
        for (int n = 0; n < 4; ++n)
            acc[m][n] = (f32x4){0.f, 0.f, 0.f, 0.f};

    for (int k0 = 0; k0 < DIM; k0 += 32) {
        {
            float4 f0 = make_float4(0.f, 0.f, 0.f, 0.f), f1 = f0;
            if (arow_ok) {
                f0 = *(const float4*)(xrow + k0 + ag * 8);
                f1 = *(const float4*)(xrow + k0 + ag * 8 + 4);
            }
            union { bf16x8 v; unsigned short u[8]; } pk;
            pk.u[0] = f2bf(f0.x); pk.u[1] = f2bf(f0.y);
            pk.u[2] = f2bf(f0.z); pk.u[3] = f2bf(f0.w);
            pk.u[4] = f2bf(f1.x); pk.u[5] = f2bf(f1.y);
            pk.u[6] = f2bf(f1.z); pk.u[7] = f2bf(f1.w);
            *(bf16x8*)(&As[ar * 40 + ag * 8]) = pk.v;
        }
        #pragma unroll
        for (int i = 0; i < 4; ++i) {
            int colb = bc + 64 * i;
            bf16x8 w = *(const bf16x8*)(Wt + (size_t)colb * DIM + k0 + bg * 8);
            *(bf16x8*)(&Bs[colb * 40 + bg * 8]) = w;
        }
        __syncthreads();

        bf16x8 afr[4], bfr[4];
        #pragma unroll
        for (int m = 0; m < 4; ++m)
            afr[m] = *(const bf16x8*)(&As[(m * 16 + lr) * 40 + lg * 8]);
        #pragma unroll
        for (int n = 0; n < 4; ++n)
            bfr[n] = *(const bf16x8*)(&Bs[(64 * wv + n * 16 + lr) * 40 + lg * 8]);
        #pragma unroll
        for (int m = 0; m < 4; ++m)
            #pragma unroll
            for (int n = 0; n < 4; ++n)
                acc[m][n] = __builtin_amdgcn_mfma_f32_16x16x32_bf16(afr[m], bfr[n], acc[m][n], 0, 0, 0);
        __syncthreads();
    }

    const float* dv = (wv < 2) ? dinv1 : dinv2;
    unsigned char* hc = hs8 + (size_t)wv * CHSZ;   // this wave's chunk
    #pragma unroll
    for (int m = 0; m < 4; ++m) {
        int row0 = m0 + m * 16 + lg * 4;
        float d[4];
        #pragma unroll
        for (int j = 0; j < 4; ++j)
            d[j] = (row0 + j < NNODES) ? dv[row0 + j] * HS_SCALE : 0.f;
        #pragma unroll
        for (int n = 0; n < 4; ++n) {
            int c = n * 16 + lr;            // chunk-local col 0..63
            #pragma unroll
            for (int j = 0; j < 4; ++j) {
                int r = row0 + j;
                if (r < NNODES)
                    hc[(size_t)r * 64 + c] = f2fp8(acc[m][n][j] * d[j]);
            }
        }
    }
}

// ---- aggregate one 64-col chunk (L2-resident 3.2MB slab, edge-balanced waves) ----
// lane-octet handles one edge's 64B row (8B/lane); octets combined via 3 shfl rounds.

__global__ __launch_bounds__(256)
void agg12c_kernel(const unsigned char* __restrict__ hsc,
                   const int* __restrict__ rowptr, const int* __restrict__ col,
                   const float* __restrict__ dinv, const float* __restrict__ bias,
                   int E, int W, unsigned short* __restrict__ hdst) {
    int w = blockIdx.x * 4 + (threadIdx.x >> 6);
    int lane = threadIdx.x & 63;
    long long EE = E;
    int q0 = (int)(EE * w / W);
    int q1 = (int)(EE * (w + 1) / W);
    int v0 = lbound(rowptr, q0);
    int v1 = (w == W - 1) ? NNODES : lbound(rowptr, q1);

    int oct = lane >> 3;           // 0..7 -> edge slot
    int lc = lane & 7;             // 8B col group: cols lc*8..lc*8+7
    float bias8[8];
    #pragma unroll
    for (int j = 0; j < 8; ++j) bias8[j] = bias[lc * 8 + j];

    for (int v = v0; v < v1; ++v) {
        int e0 = rowptr[v], e1 = rowptr[v + 1];
        f32x2 acc[4];
        #pragma unroll
        for (int i = 0; i < 4; ++i) acc[i] = (f32x2){0.f, 0.f};
        int e = e0;
        for (; e + 16 <= e1; e += 16) {
            int sA = col[e + oct];
            int sB = col[e + 8 + oct];
            uint2 uA = *(const uint2*)(hsc + (size_t)sA * 64 + lc * 8);
            uint2 uB = *(const uint2*)(hsc + (size_t)sB * 64 + lc * 8);
            fp8add2(uA.x, acc[0], acc[1]); fp8add2(uA.y, acc[2], acc[3]);
            fp8add2(uB.x, acc[0], acc[1]); fp8add2(uB.y, acc[2], acc[3]);
        }
        if (e + 8 <= e1) {
            int sA = col[e + oct];
            uint2 uA = *(const uint2*)(hsc + (size_t)sA * 64 + lc * 8);
            fp8add2(uA.x, acc[0], acc[1]); fp8add2(uA.y, acc[2], acc[3]);
            e += 8;
        }
        if (e < e1 && oct < e1 - e) {
            int sA = col[e + oct];
            uint2 uA = *(const uint2*)(hsc + (size_t)sA * 64 + lc * 8);
            fp8add2(uA.x, acc[0], acc[1]); fp8add2(uA.y, acc[2], acc[3]);
        }
        #pragma unroll
        for (int i = 0; i < 4; ++i) {
            #pragma unroll
            for (int off = 8; off <= 32; off <<= 1) {
                acc[i][0] += __shfl_xor(acc[i][0], off);
                acc[i][1] += __shfl_xor(acc[i][1], off);
            }
        }
        // self term (post-reduce, consistent across lanes)
        uint2 su = *(const uint2*)(hsc + (size_t)v * 64 + lc * 8);
        fp8add2(su.x, acc[0], acc[1]); fp8add2(su.y, acc[2], acc[3]);
        float sc = dinv[v] * HS_ISCALE;
        if (oct == 0) {
            unsigned int res[4];
            #pragma unroll
            for (int p = 0; p < 4; ++p) {
                float r0 = fmaxf(acc[p][0] * sc + bias8[2 * p + 0], 0.f);
                float r1 = fmaxf(acc[p][1] * sc + bias8[2 * p + 1], 0.f);
                res[p] = (unsigned int)f2bf(r0) | ((unsigned int)f2bf(r1) << 16);
            }
            uint4 st = {res[0], res[1], res[2], res[3]};
            *(uint4*)(hdst + (size_t)v * 256 + lc * 8) = st;
        }
    }
}

// ---- layer-3 GEMM: gs = bf16(dinv1 * (hcat @ W3)), hcat bf16 ----

__global__ __launch_bounds__(256)
void gemm3_kernel(const unsigned short* __restrict__ hcat, const float* __restrict__ W3,
                  const float* __restrict__ dinv1, unsigned short* __restrict__ gs) {
    __shared__ float Ws[256 * 32];
    int tid = threadIdx.x;
    for (int i = tid * 4; i < 256 * 32; i += 1024)
        *(float4*)(Ws + i) = *(const float4*)(W3 + i);
    __syncthreads();
    int c = tid & 31, ty = tid >> 5;
    int r = blockIdx.x * 8 + ty;
    if (r >= NNODES) return;
    const unsigned short* hr = hcat + (size_t)r * 256;
    float acc = 0.f;
    #pragma unroll 2
    for (int k = 0; k < 256; k += 8) {
        uint4 u = *(const uint4*)(hr + k);
        acc += bf2f((unsigned short)(u.x & 0xffff)) * Ws[(k + 0) * 32 + c]
             + bf2f((unsigned short)(u.x >> 16))    * Ws[(k + 1) * 32 + c]
             + bf2f((unsigned short)(u.y & 0xffff)) * Ws[(k + 2) * 32 + c]
             + bf2f((unsigned short)(u.y >> 16))    * Ws[(k + 3) * 32 + c]
             + bf2f((unsigned short)(u.z & 0xffff)) * Ws[(k + 4) * 32 + c]
             + bf2f((unsigned short)(u.z >> 16))    * Ws[(k + 5) * 32 + c]
             + bf2f((unsigned short)(u.w & 0xffff)) * Ws[(k + 6) * 32 + c]
             + bf2f((unsigned short)(u.w >> 16))    * Ws[(k + 7) * 32 + c];
    }
    gs[(size_t)r * 32 + c] = f2bf(acc * dinv1[r]);
}

// ---- layer-3 aggregation + bias + log_softmax (edge-balanced, gs bf16) ----

__global__ __launch_bounds__(256)
void agg3_kernel(const unsigned short* __restrict__ gs, const int* __restrict__ rowptr1,
                 const int* __restrict__ col1, const float* __restrict__ dinv1,
                 const float* __restrict__ b3, float* __restrict__ out, int E1) {
    int gw = blockIdx.x * 4 + (threadIdx.x >> 6);
    int lane = threadIdx.x & 63;
    long long E = E1;
    int q0 = (int)(E * gw / A3_WAVES);
    int q1 = (int)(E * (gw + 1) / A3_WAVES);
    int v0 = lbound(rowptr1, q0);
    int v1 = (gw == A3_WAVES - 1) ? NNODES : lbound(rowptr1, q1);

    int oct = lane >> 3;         // 0..7 -> edge slot
    int lc = lane & 7;           // col group (4 vals each)
    float4 b3v = *(const float4*)(b3 + lc * 4);

    for (int v = v0; v < v1; ++v) {
        int e0 = rowptr1[v], e1 = rowptr1[v + 1];
        float a0 = 0.f, a1 = 0.f, a2 = 0.f, a3 = 0.f;
        int e = e0;
        #pragma unroll 2
        for (; e + 8 <= e1; e += 8) {
            int srco = col1[e + oct];
            uint2 u = *(const uint2*)(gs + (size_t)srco * 32 + lc * 4);
            a0 += bf2f((unsigned short)(u.x & 0xffff));
            a1 += bf2f((unsigned short)(u.x >> 16));
            a2 += bf2f((unsigned short)(u.y & 0xffff));
            a3 += bf2f((unsigned short)(u.y >> 16));
        }
        if (e < e1) {
            int r = e1 - e;
            if (oct < r) {
                int srco = col1[e + oct];
                uint2 u = *(const uint2*)(gs + (size_t)srco * 32 + lc * 4);
                a0 += bf2f((unsigned short)(u.x & 0xffff));
                a1 += bf2f((unsigned short)(u.x >> 16));
                a2 += bf2f((unsigned short)(u.y & 0xffff));
                a3 += bf2f((unsigned short)(u.y >> 16));
            }
        }
        #pragma unroll
        for (int off = 32; off >= 8; off >>= 1) {
            a0 += __shfl_xor(a0, off); a1 += __shfl_xor(a1, off);
            a2 += __shfl_xor(a2, off); a3 += __shfl_xor(a3, off);
        }
        uint2 su = *(const uint2*)(gs + (size_t)v * 32 + lc * 4);
        a0 += bf2f((unsigned short)(su.x & 0xffff));
        a1 += bf2f((unsigned short)(su.x >> 16));
        a2 += bf2f((unsigned short)(su.y & 0xffff));
        a3 += bf2f((unsigned short)(su.y >> 16));
        float d = dinv1[v];
        float l0 = a0 * d + b3v.x, l1 = a1 * d + b3v.y;
        float l2 = a2 * d + b3v.z, l3 = a3 * d + b3v.w;
        float m = fmaxf(fmaxf(l0, l1), fmaxf(l2, l3));
        #pragma unroll
        for (int off = 1; off <= 4; off <<= 1) m = fmaxf(m, __shfl_xor(m, off));
        float s = expf(l0 - m) + expf(l1 - m) + expf(l2 - m) + expf(l3 - m);
        #pragma unroll
        for (int off = 1; off <= 4; off <<= 1) s += __shfl_xor(s, off);
        float lg = logf(s);
        if (oct == 0) {
            float4 o = make_float4(l0 - m - lg, l1 - m - lg, l2 - m - lg, l3 - m - lg);
            *(float4*)(out + (size_t)v * 32 + lc * 4) = o;
        }
    }
}

extern "C" void kernel_launch(void* const* d_in, const int* in_sizes, int n_in,
                              void* d_out, int out_size, void* d_ws, size_t ws_size,
                              hipStream_t stream) {
    const float* x  = (const float*)d_in[0];
    const int* ei1  = (const int*)d_in[1];
    const int* ei2  = (const int*)d_in[2];
    const float* W1 = (const float*)d_in[3];
    const float* b1 = (const float*)d_in[4];
    const float* W2 = (const float*)d_in[5];
    const float* b2 = (const float*)d_in[6];
    const float* W3 = (const float*)d_in[7];
    const float* b3 = (const float*)d_in[8];
    float* out = (float*)d_out;

    int E1 = in_sizes[1] / 2;
    int E2 = in_sizes[2] / 2;
    const int* src1 = ei1;       const int* dst1 = ei1 + E1;
    const int* src2 = ei2;       const int* dst2 = ei2 + E2;
    int nb1 = (E1 + CHUNK - 1) / CHUNK;
    int nb2 = (E2 + CHUNK - 1) / CHUNK;

    char* w = (char*)d_ws;
    auto alloc = [&](size_t bytes) -> char* {
        char* p = w; w += (bytes + 255) & ~(size_t)255; return p;
    };
    int* hist1   = (int*)alloc((size_t)NBINS * nb1 * 4);
    int* hist2   = (int*)alloc((size_t)NBINS * nb2 * 4);
    int* bs1     = (int*)alloc((size_t)(NBINS + 1) * 4);
    int* bs2     = (int*)alloc((size_t)(NBINS + 1) * 4);
    int* rowptr1 = (int*)alloc((size_t)(NNODES + 1) * 4);
    int* rowptr2 = (int*)alloc((size_t)(NNODES + 1) * 4);
    float* dinv1 = (float*)alloc((size_t)NNODES * 4);
    float* dinv2 = (float*)alloc((size_t)NNODES * 4);
    int* col1    = (int*)alloc((size_t)E1 * 4);
    int* col2    = (int*)alloc((size_t)E2 * 4);
    unsigned short* Wt = (unsigned short*)alloc((size_t)256 * DIM * 2);
    unsigned char* hs8 = (unsigned char*)alloc(4 * CHSZ);
    unsigned short* gs = (unsigned short*)alloc((size_t)NNODES * 32 * 2);
    unsigned short* hcat = (unsigned short*)alloc((size_t)NNODES * 256 * 2);
    // binned arrays alias hcat (dead before agg12 writes hcat); 19.4MB <= 25.6MB
    unsigned int* binned1 = (unsigned int*)hcat;
    unsigned int* binned2 = binned1 + E1;

    hist_kernel<<<nb1, 256, 0, stream>>>(dst1, E1, nb1, hist1);
    hist_kernel<<<nb2, 256, 0, stream>>>(dst2, E2, nb2, hist2);
    scan_row_kernel<<<NBINS, 256, 0, stream>>>(hist1, nb1, bs1);
    scan_row_kernel<<<NBINS, 256, 0, stream>>>(hist2, nb2, bs2);
    scan_row_kernel<<<1, 256, 0, stream>>>(bs1, NBINS, bs1 + NBINS);
    scan_row_kernel<<<1, 256, 0, stream>>>(bs2, NBINS, bs2 + NBINS);
    scatter_kernel<<<nb1, 256, 0, stream>>>(src1, dst1, E1, nb1, hist1, bs1, binned1);
    scatter_kernel<<<nb2, 256, 0, stream>>>(src2, dst2, E2, nb2, hist2, bs2, binned2);
    binfill_kernel<<<NBINS, 256, 0, stream>>>(binned1, bs1, rowptr1, dinv1, col1, E1);
    binfill_kernel<<<NBINS, 256, 0, stream>>>(binned2, bs2, rowptr2, dinv2, col2, E2);

    convW_kernel<<<DIM, 256, 0, stream>>>(W1, W2, Wt);
    gemm12_mfma_kernel<<<(NNODES + 63) / 64, 256, 0, stream>>>(x, Wt, dinv1, dinv2, hs8);
    // four L2-resident chunk passes: {g1-lo, g1-hi, g2-lo, g2-hi}
    agg12c_kernel<<<AGG_WAVES_G1 / 4, 256, 0, stream>>>(
        hs8 + 0 * CHSZ, rowptr1, col1, dinv1, b1,      E1, AGG_WAVES_G1, hcat + 0);
    agg12c_kernel<<<AGG_WAVES_G1 / 4, 256, 0, stream>>>(
        hs8 + 1 * CHSZ, rowptr1, col1, dinv1, b1 + 64, E1, AGG_WAVES_G1, hcat + 64);
    agg12c_kernel<<<AGG_WAVES_G2 / 4, 256, 0, stream>>>(
        hs8 + 2 * CHSZ, rowptr2, col2, dinv2, b2,      E2, AGG_WAVES_G2, hcat + 128);
    agg12c_kernel<<<AGG_WAVES_G2 / 4, 256, 0, stream>>>(
        hs8 + 3 * CHSZ, rowptr2, col2, dinv2, b2 + 64, E2, AGG_WAVES_G2, hcat + 192);
    gemm3_kernel<<<NNODES / 8, 256, 0, stream>>>(hcat, W3, dinv1, gs);
    agg3_kernel<<<A3_WAVES / 4, 256, 0, stream>>>(gs, rowptr1, col1, dinv1, b3, out, E1);
}

// Round 7
// 365.371 us; speedup vs baseline: 1.2498x; 1.2498x over previous
//
#include <hip/hip_runtime.h>

#define NNODES 50000
#define DIM 512
#define HID 128
#define NCLS 32
#define NBINS 196          // ceil(50000 / 256), bin = dst >> 8
#define CHUNK 8192         // edges per block in hist/scatter passes
#define AGG_WAVES_G1 2048
#define AGG_WAVES_G2 4096
#define A3_WAVES 4096
#define HS_SCALE 64.0f
#define HS_ISCALE 0.015625f

typedef __attribute__((ext_vector_type(8))) short bf16x8;
typedef __attribute__((ext_vector_type(4))) float f32x4;
typedef __attribute__((ext_vector_type(2))) float f32x2;

__device__ __forceinline__ unsigned short f2bf(float f) {
    union { float f; unsigned int u; } a; a.f = f;
    unsigned int u = a.u;
    u += 0x7fff + ((u >> 16) & 1);   // round-to-nearest-even
    return (unsigned short)(u >> 16);
}
__device__ __forceinline__ float bf2f(unsigned short h) {
    union { unsigned int u; float f; } a; a.u = ((unsigned int)h) << 16;
    return a.f;
}
// f32 -> fp8 e4m3 (OCP on gfx950), RNE
__device__ __forceinline__ unsigned char f2fp8(float f) {
    int p = __builtin_amdgcn_cvt_pk_fp8_f32(f, 0.f, 0, false);
    return (unsigned char)(p & 0xff);
}
// 4 packed fp8 -> two f32x2 accumulators (v_pk_add_f32)
__device__ __forceinline__ void fp8add2(unsigned int u, f32x2& a01, f32x2& a23) {
    a01 += __builtin_amdgcn_cvt_pk_f32_fp8((int)u, false);
    a23 += __builtin_amdgcn_cvt_pk_f32_fp8((int)u, true);
}
// min v in [0,NNODES] with rp[v] >= q
__device__ __forceinline__ int lbound(const int* __restrict__ rp, int q) {
    int lo = 0, hi = NNODES;
    while (lo < hi) { int mid = (lo + hi) >> 1; if (rp[mid] >= q) hi = mid; else lo = mid + 1; }
    return lo;
}

// ============ deterministic CSR build: counting sort by dst ============

__global__ __launch_bounds__(256)
void hist_kernel(const int* __restrict__ dst, int E, int nb, int* __restrict__ hist) {
    __shared__ int h[NBINS];
    int tid = threadIdx.x;
    for (int i = tid; i < NBINS; i += 256) h[i] = 0;
    __syncthreads();
    int e0 = blockIdx.x * CHUNK;
    int e1 = min(E, e0 + CHUNK);
    for (int e = e0 + tid; e < e1; e += 256)
        atomicAdd(&h[dst[e] >> 8], 1);
    __syncthreads();
    for (int i = tid; i < NBINS; i += 256)
        hist[(size_t)i * nb + blockIdx.x] = h[i];
}

__global__ __launch_bounds__(256)
void scan_row_kernel(int* __restrict__ data, int n, int* __restrict__ total) {
    int* row = data + (size_t)blockIdx.x * n;
    __shared__ int wsum[4];
    int tid = threadIdx.x, lane = tid & 63, wid = tid >> 6;
    int base = 0;
    for (int start = 0; start < n; start += 256) {
        int i = start + tid;
        int v = (i < n) ? row[i] : 0;
        int x = v;
        #pragma unroll
        for (int off = 1; off < 64; off <<= 1) {
            int t = __shfl_up(x, off);
            if (lane >= off) x += t;
        }
        if (lane == 63) wsum[wid] = x;
        __syncthreads();
        int woff = 0, tot = 0;
        #pragma unroll
        for (int w = 0; w < 4; ++w) { int s = wsum[w]; if (w < wid) woff += s; tot += s; }
        __syncthreads();
        if (i < n) row[i] = base + woff + x - v;
        base += tot;
    }
    if (tid == 0) total[blockIdx.x] = base;
}

__global__ __launch_bounds__(256)
void scatter_kernel(const int* __restrict__ src, const int* __restrict__ dst, int E, int nb,
                    const int* __restrict__ hist, const int* __restrict__ binStart,
                    unsigned int* __restrict__ binned) {
    __shared__ int cur[NBINS];
    int tid = threadIdx.x;
    for (int i = tid; i < NBINS; i += 256)
        cur[i] = hist[(size_t)i * nb + blockIdx.x] + binStart[i];
    __syncthreads();
    int e0 = blockIdx.x * CHUNK;
    int e1 = min(E, e0 + CHUNK);
    for (int e = e0 + tid; e < e1; e += 256) {
        int d = dst[e];
        int b = d >> 8;
        int p = atomicAdd(&cur[b], 1);   // LDS atomic only
        binned[p] = ((unsigned int)(d & 255) << 16) | (unsigned int)src[e];
    }
}

__global__ __launch_bounds__(256)
void binfill_kernel(const unsigned int* __restrict__ binned, const int* __restrict__ binStart,
                    int* __restrict__ rowptr, float* __restrict__ dinv, int* __restrict__ col,
                    int totalE) {
    __shared__ int cnt[256], cur[256];
    __shared__ int wsum[4];
    int b = blockIdx.x;
    int tid = threadIdx.x, lane = tid & 63, wid = tid >> 6;
    int s = binStart[b], e = binStart[b + 1];
    cnt[tid] = 0;
    __syncthreads();
    for (int i = s + tid; i < e; i += 256)
        atomicAdd(&cnt[binned[i] >> 16], 1);
    __syncthreads();
    int v = cnt[tid];
    int x = v;
    #pragma unroll
    for (int off = 1; off < 64; off <<= 1) {
        int t = __shfl_up(x, off);
        if (lane >= off) x += t;
    }
    if (lane == 63) wsum[wid] = x;
    __syncthreads();
    int woff = 0;
    #pragma unroll
    for (int w = 0; w < 4; ++w) if (w < wid) woff += wsum[w];
    int ex = woff + x - v;               // exclusive prefix within bin
    cur[tid] = ex;
    __syncthreads();
    int node = b * 256 + tid;
    if (node < NNODES) {
        rowptr[node] = s + ex;
        dinv[node] = rsqrtf((float)v + 1.0f);   // +1 self-loop
    }
    if (b == 0 && tid == 0) rowptr[NNODES] = totalE;
    for (int i = s + tid; i < e; i += 256) {
        unsigned int pk = binned[i];
        int ld = pk >> 16;
        int p = atomicAdd(&cur[ld], 1);  // LDS atomic only
        col[s + p] = (int)(pk & 0xffff);
    }
}

// ---- W permute+cast: Wt2[kt][kg][c][kidx] bf16, c<128 -> W1 col, else W2 col ----
// k = kt*32 + kg*8 + kidx; ushort idx = kt*8192 + kg*2048 + c*8 + kidx.

__global__ __launch_bounds__(256)
void convW_kernel(const float* __restrict__ W1, const float* __restrict__ W2,
                  unsigned short* __restrict__ Wt2) {
    int k = blockIdx.x;          // 0..511
    int c = threadIdx.x;         // 0..255
    float v = (c < HID) ? W1[(size_t)k * HID + c] : W2[(size_t)k * HID + (c - HID)];
    int kt = k >> 5, kg = (k >> 3) & 3, kidx = k & 7;
    Wt2[(size_t)kt * 8192 + kg * 2048 + c * 8 + kidx] = f2bf(v);
}

// ---- W3 permute+cast: Wt3[kt][kg][c][kidx] bf16 (k in [0,256), c in [0,32)) ----

__global__ __launch_bounds__(256)
void convW3_kernel(const float* __restrict__ W3, unsigned short* __restrict__ Wt3) {
    int idx = blockIdx.x * 256 + threadIdx.x;   // 0..8191
    int k = idx >> 5, c = idx & 31;
    int kt = k >> 5, kg = (k >> 3) & 3, kidx = k & 7;
    Wt3[(kt * 4 + kg) * 256 + c * 8 + kidx] = f2bf(W3[(size_t)k * NCLS + c]);
}

// ---- MFMA GEMM: hs8[r][c] = fp8(64 * dinv_g[r] * (x@Wg)[r][c]) ----
// 4 waves x 16 rows; full N=256 per wave (16 n-frags). A direct global->reg->cvt.
// B 16KB/kt double-buffered in LDS [kg][col][8] (2-way bank aliasing = free).

__global__ __launch_bounds__(256)
void gemm12_mfma_kernel(const float* __restrict__ x, const unsigned short* __restrict__ Wt2,
                        const float* __restrict__ dinv1, const float* __restrict__ dinv2,
                        unsigned char* __restrict__ hs8) {
    __shared__ unsigned short Bs[2][8192];   // 2 x 16KB
    int tid = threadIdx.x;
    int wv = tid >> 6, l = tid & 63;
    int lr = l & 15, lg = l >> 4;
    int m0 = blockIdx.x * 64;
    int row = m0 + wv * 16 + lr;
    int rowc = min(row, NNODES - 1);
    const float* xrow = x + (size_t)rowc * DIM;

    f32x4 acc[16];
    #pragma unroll
    for (int n = 0; n < 16; ++n) acc[n] = (f32x4){0.f, 0.f, 0.f, 0.f};

    uint4 bn[4];
    float4 a0, a1, a0n, a1n;
    // preload kt=0
    #pragma unroll
    for (int p = 0; p < 4; ++p)
        bn[p] = *(const uint4*)(Wt2 + p * 2048 + tid * 8);
    a0 = *(const float4*)(xrow + lg * 8);
    a1 = *(const float4*)(xrow + lg * 8 + 4);
    #pragma unroll
    for (int p = 0; p < 4; ++p)
        *(uint4*)(&Bs[0][p * 2048 + tid * 8]) = bn[p];
    __syncthreads();

    int cur = 0;
    for (int kt = 0; kt < 16; ++kt) {
        if (kt < 15) {   // prefetch next B tile + next A segment (hides under MFMA)
            #pragma unroll
            for (int p = 0; p < 4; ++p)
                bn[p] = *(const uint4*)(Wt2 + (size_t)(kt + 1) * 8192 + p * 2048 + tid * 8);
            a0n = *(const float4*)(xrow + (kt + 1) * 32 + lg * 8);
            a1n = *(const float4*)(xrow + (kt + 1) * 32 + lg * 8 + 4);
        }
        union { bf16x8 v; unsigned short u[8]; } af;
        af.u[0] = f2bf(a0.x); af.u[1] = f2bf(a0.y);
        af.u[2] = f2bf(a0.z); af.u[3] = f2bf(a0.w);
        af.u[4] = f2bf(a1.x); af.u[5] = f2bf(a1.y);
        af.u[6] = f2bf(a1.z); af.u[7] = f2bf(a1.w);
        #pragma unroll
        for (int nf = 0; nf < 16; ++nf) {
            bf16x8 bf = *(const bf16x8*)(&Bs[cur][lg * 2048 + (nf * 16 + lr) * 8]);
            acc[nf] = __builtin_amdgcn_mfma_f32_16x16x32_bf16(af.v, bf, acc[nf], 0, 0, 0);
        }
        if (kt < 15) {
            #pragma unroll
            for (int p = 0; p < 4; ++p)
                *(uint4*)(&Bs[cur ^ 1][p * 2048 + tid * 8]) = bn[p];
            __syncthreads();
            cur ^= 1;
            a0 = a0n; a1 = a1n;
        }
    }

    // epilogue: C layout col=lane&15, row=(lane>>4)*4+reg
    int row0 = m0 + wv * 16 + lg * 4;
    float d1[4], d2[4];
    #pragma unroll
    for (int j = 0; j < 4; ++j) {
        bool ok = (row0 + j) < NNODES;
        d1[j] = ok ? dinv1[row0 + j] * HS_SCALE : 0.f;
        d2[j] = ok ? dinv2[row0 + j] * HS_SCALE : 0.f;
    }
    #pragma unroll
    for (int nf = 0; nf < 16; ++nf) {
        int c = nf * 16 + lr;
        const float* d = (nf < 8) ? d1 : d2;
        #pragma unroll
        for (int j = 0; j < 4; ++j) {
            int r = row0 + j;
            if (r < NNODES)
                hs8[(size_t)r * 256 + c] = f2fp8(acc[nf][j] * d[j]);
        }
    }
}

// ---- aggregate layers 1&2 (edge-balanced waves, fp8 gathers, bf16 out) ----

__global__ __launch_bounds__(256)
void agg12_kernel(const unsigned char* __restrict__ hs8,
                  const int* __restrict__ rowptr1, const int* __restrict__ col1,
                  const int* __restrict__ rowptr2, const int* __restrict__ col2,
                  const float* __restrict__ dinv1, const float* __restrict__ dinv2,
                  const float* __restrict__ b1, const float* __restrict__ b2,
                  int E1, int E2, unsigned short* __restrict__ hcat) {
    int gw = blockIdx.x * 4 + (threadIdx.x >> 6);
    int lane = threadIdx.x & 63;
    int g, w, W; long long E;
    const int *rowptr, *col; const float *dinv, *bias;
    if (gw < AGG_WAVES_G1) {
        g = 0; w = gw; W = AGG_WAVES_G1; E = E1;
        rowptr = rowptr1; col = col1; dinv = dinv1; bias = b1;
    } else {
        g = 1; w = gw - AGG_WAVES_G1; W = AGG_WAVES_G2; E = E2;
        rowptr = rowptr2; col = col2; dinv = dinv2; bias = b2;
    }
    int q0 = (int)(E * w / W);
    int q1 = (int)(E * (w + 1) / W);
    int v0 = lbound(rowptr, q0);
    int v1 = (w == W - 1) ? NNODES : lbound(rowptr, q1);

    int quarter = lane >> 4;       // 0..3 -> edge slot
    int lc = lane & 15;            // col group (8 fp8 each)
    float bias8[8];
    #pragma unroll
    for (int j = 0; j < 8; ++j) bias8[j] = bias[lc * 8 + j];
    const unsigned char* hsg = hs8 + g * 128;

    for (int v = v0; v < v1; ++v) {
        int e0 = rowptr[v], e1 = rowptr[v + 1];
        f32x2 acc[4];
        #pragma unroll
        for (int i = 0; i < 4; ++i) acc[i] = (f32x2){0.f, 0.f};
        int e = e0;
        #pragma unroll 2
        for (; e + 8 <= e1; e += 8) {
            int sA = col[e + quarter];
            int sB = col[e + 4 + quarter];
            uint2 uA = *(const uint2*)(hsg + (size_t)sA * 256 + lc * 8);
            uint2 uB = *(const uint2*)(hsg + (size_t)sB * 256 + lc * 8);
            fp8add2(uA.x, acc[0], acc[1]); fp8add2(uA.y, acc[2], acc[3]);
            fp8add2(uB.x, acc[0], acc[1]); fp8add2(uB.y, acc[2], acc[3]);
        }
        if (e + 4 <= e1) {
            int sA = col[e + quarter];
            uint2 uA = *(const uint2*)(hsg + (size_t)sA * 256 + lc * 8);
            fp8add2(uA.x, acc[0], acc[1]); fp8add2(uA.y, acc[2], acc[3]);
            e += 4;
        }
        if (e < e1 && quarter < e1 - e) {
            int sA = col[e + quarter];
            uint2 uA = *(const uint2*)(hsg + (size_t)sA * 256 + lc * 8);
            fp8add2(uA.x, acc[0], acc[1]); fp8add2(uA.y, acc[2], acc[3]);
        }
        #pragma unroll
        for (int i = 0; i < 4; ++i) {
            #pragma unroll
            for (int off = 16; off <= 32; off <<= 1) {
                acc[i][0] += __shfl_xor(acc[i][0], off);
                acc[i][1] += __shfl_xor(acc[i][1], off);
            }
        }
        // self term (post-reduce, consistent across lanes)
        uint2 su = *(const uint2*)(hsg + (size_t)v * 256 + lc * 8);
        fp8add2(su.x, acc[0], acc[1]); fp8add2(su.y, acc[2], acc[3]);
        float sc = dinv[v] * HS_ISCALE;
        if (quarter == 0) {
            unsigned int res[4];
            #pragma unroll
            for (int p = 0; p < 4; ++p) {
                float r0 = fmaxf(acc[p][0] * sc + bias8[2 * p + 0], 0.f);
                float r1 = fmaxf(acc[p][1] * sc + bias8[2 * p + 1], 0.f);
                res[p] = (unsigned int)f2bf(r0) | ((unsigned int)f2bf(r1) << 16);
            }
            uint4 st = {res[0], res[1], res[2], res[3]};
            *(uint4*)(hcat + (size_t)v * 256 + g * 128 + lc * 8) = st;
        }
    }
}

// ---- layer-3 MFMA GEMM: gs = bf16(dinv1 * (hcat @ W3)) ----
// 4 waves x 64 rows; W3 (16KB bf16) LDS-resident, staged once. A direct from hcat.

__global__ __launch_bounds__(256)
void gemm3_mfma_kernel(const unsigned short* __restrict__ hcat,
                       const unsigned short* __restrict__ Wt3,
                       const float* __restrict__ dinv1, unsigned short* __restrict__ gs) {
    __shared__ unsigned short Ws[8192];   // [kt*4+kg][c][8] = 16KB
    int tid = threadIdx.x;
    #pragma unroll
    for (int p = 0; p < 4; ++p)
        *(uint4*)(&Ws[p * 2048 + tid * 8]) = *(const uint4*)(Wt3 + p * 2048 + tid * 8);
    __syncthreads();

    int wv = tid >> 6, l = tid & 63;
    int lr = l & 15, lg = l >> 4;
    int rbase = blockIdx.x * 256 + wv * 64;

    f32x4 acc[4][2];
    #pragma unroll
    for (int m = 0; m < 4; ++m)
        #pragma unroll
        for (int n = 0; n < 2; ++n)
            acc[m][n] = (f32x4){0.f, 0.f, 0.f, 0.f};

    #pragma unroll
    for (int kt = 0; kt < 8; ++kt) {
        #pragma unroll
        for (int m = 0; m < 4; ++m) {
            int rA = min(rbase + m * 16 + lr, NNODES - 1);
            bf16x8 af = *(const bf16x8*)(hcat + (size_t)rA * 256 + kt * 32 + lg * 8);
            #pragma unroll
            for (int n = 0; n < 2; ++n) {
                bf16x8 bf = *(const bf16x8*)(&Ws[(kt * 4 + lg) * 256 + (n * 16 + lr) * 8]);
                acc[m][n] = __builtin_amdgcn_mfma_f32_16x16x32_bf16(af, bf, acc[m][n], 0, 0, 0);
            }
        }
    }

    #pragma unroll
    for (int m = 0; m < 4; ++m) {
        int row0 = rbase + m * 16 + lg * 4;
        float d[4];
        #pragma unroll
        for (int j = 0; j < 4; ++j)
            d[j] = (row0 + j < NNODES) ? dinv1[row0 + j] : 0.f;
        #pragma unroll
        for (int n = 0; n < 2; ++n) {
            int c = n * 16 + lr;
            #pragma unroll
            for (int j = 0; j < 4; ++j) {
                int r = row0 + j;
                if (r < NNODES)
                    gs[(size_t)r * 32 + c] = f2bf(acc[m][n][j] * d[j]);
            }
        }
    }
}

// ---- layer-3 aggregation + bias + log_softmax (edge-balanced, gs bf16) ----

__global__ __launch_bounds__(256)
void agg3_kernel(const unsigned short* __restrict__ gs, const int* __restrict__ rowptr1,
                 const int* __restrict__ col1, const float* __restrict__ dinv1,
                 const float* __restrict__ b3, float* __restrict__ out, int E1) {
    int gw = blockIdx.x * 4 + (threadIdx.x >> 6);
    int lane = threadIdx.x & 63;
    long long E = E1;
    int q0 = (int)(E * gw / A3_WAVES);
    int q1 = (int)(E * (gw + 1) / A3_WAVES);
    int v0 = lbound(rowptr1, q0);
    int v1 = (gw == A3_WAVES - 1) ? NNODES : lbound(rowptr1, q1);

    int oct = lane >> 3;         // 0..7 -> edge slot
    int lc = lane & 7;           // col group (4 vals each)
    float4 b3v = *(const float4*)(b3 + lc * 4);

    for (int v = v0; v < v1; ++v) {
        int e0 = rowptr1[v], e1 = rowptr1[v + 1];
        float a0 = 0.f, a1 = 0.f, a2 = 0.f, a3 = 0.f;
        int e = e0;
        #pragma unroll 2
        for (; e + 8 <= e1; e += 8) {
            int srco = col1[e + oct];
            uint2 u = *(const uint2*)(gs + (size_t)srco * 32 + lc * 4);
            a0 += bf2f((unsigned short)(u.x & 0xffff));
            a1 += bf2f((unsigned short)(u.x >> 16));
            a2 += bf2f((unsigned short)(u.y & 0xffff));
            a3 += bf2f((unsigned short)(u.y >> 16));
        }
        if (e < e1) {
            int r = e1 - e;
            if (oct < r) {
                int srco = col1[e + oct];
                uint2 u = *(const uint2*)(gs + (size_t)srco * 32 + lc * 4);
                a0 += bf2f((unsigned short)(u.x & 0xffff));
                a1 += bf2f((unsigned short)(u.x >> 16));
                a2 += bf2f((unsigned short)(u.y & 0xffff));
                a3 += bf2f((unsigned short)(u.y >> 16));
            }
        }
        #pragma unroll
        for (int off = 32; off >= 8; off >>= 1) {
            a0 += __shfl_xor(a0, off); a1 += __shfl_xor(a1, off);
            a2 += __shfl_xor(a2, off); a3 += __shfl_xor(a3, off);
        }
        uint2 su = *(const uint2*)(gs + (size_t)v * 32 + lc * 4);
        a0 += bf2f((unsigned short)(su.x & 0xffff));
        a1 += bf2f((unsigned short)(su.x >> 16));
        a2 += bf2f((unsigned short)(su.y & 0xffff));
        a3 += bf2f((unsigned short)(su.y >> 16));
        float d = dinv1[v];
        float l0 = a0 * d + b3v.x, l1 = a1 * d + b3v.y;
        float l2 = a2 * d + b3v.z, l3 = a3 * d + b3v.w;
        float m = fmaxf(fmaxf(l0, l1), fmaxf(l2, l3));
        #pragma unroll
        for (int off = 1; off <= 4; off <<= 1) m = fmaxf(m, __shfl_xor(m, off));
        float s = expf(l0 - m) + expf(l1 - m) + expf(l2 - m) + expf(l3 - m);
        #pragma unroll
        for (int off = 1; off <= 4; off <<= 1) s += __shfl_xor(s, off);
        float lg = logf(s);
        if (oct == 0) {
            float4 o = make_float4(l0 - m - lg, l1 - m - lg, l2 - m - lg, l3 - m - lg);
            *(float4*)(out + (size_t)v * 32 + lc * 4) = o;
        }
    }
}

extern "C" void kernel_launch(void* const* d_in, const int* in_sizes, int n_in,
                              void* d_out, int out_size, void* d_ws, size_t ws_size,
                              hipStream_t stream) {
    const float* x  = (const float*)d_in[0];
    const int* ei1  = (const int*)d_in[1];
    const int* ei2  = (const int*)d_in[2];
    const float* W1 = (const float*)d_in[3];
    const float* b1 = (const float*)d_in[4];
    const float* W2 = (const float*)d_in[5];
    const float* b2 = (const float*)d_in[6];
    const float* W3 = (const float*)d_in[7];
    const float* b3 = (const float*)d_in[8];
    float* out = (float*)d_out;

    int E1 = in_sizes[1] / 2;
    int E2 = in_sizes[2] / 2;
    const int* src1 = ei1;       const int* dst1 = ei1 + E1;
    const int* src2 = ei2;       const int* dst2 = ei2 + E2;
    int nb1 = (E1 + CHUNK - 1) / CHUNK;
    int nb2 = (E2 + CHUNK - 1) / CHUNK;

    char* w = (char*)d_ws;
    auto alloc = [&](size_t bytes) -> char* {
        char* p = w; w += (bytes + 255) & ~(size_t)255; return p;
    };
    int* hist1   = (int*)alloc((size_t)NBINS * nb1 * 4);
    int* hist2   = (int*)alloc((size_t)NBINS * nb2 * 4);
    int* bs1     = (int*)alloc((size_t)(NBINS + 1) * 4);
    int* bs2     = (int*)alloc((size_t)(NBINS + 1) * 4);
    int* rowptr1 = (int*)alloc((size_t)(NNODES + 1) * 4);
    int* rowptr2 = (int*)alloc((size_t)(NNODES + 1) * 4);
    float* dinv1 = (float*)alloc((size_t)NNODES * 4);
    float* dinv2 = (float*)alloc((size_t)NNODES * 4);
    int* col1    = (int*)alloc((size_t)E1 * 4);
    int* col2    = (int*)alloc((size_t)E2 * 4);
    unsigned short* Wt2 = (unsigned short*)alloc((size_t)256 * DIM * 2);
    unsigned short* Wt3 = (unsigned short*)alloc((size_t)256 * NCLS * 2);
    unsigned char* hs8 = (unsigned char*)alloc((size_t)NNODES * 256);
    unsigned short* gs = (unsigned short*)alloc((size_t)NNODES * 32 * 2);
    unsigned short* hcat = (unsigned short*)alloc((size_t)NNODES * 256 * 2);
    // binned arrays alias hcat (dead before agg12 writes hcat); 19.4MB <= 25.6MB
    unsigned int* binned1 = (unsigned int*)hcat;
    unsigned int* binned2 = binned1 + E1;

    hist_kernel<<<nb1, 256, 0, stream>>>(dst1, E1, nb1, hist1);
    hist_kernel<<<nb2, 256, 0, stream>>>(dst2, E2, nb2, hist2);
    scan_row_kernel<<<NBINS, 256, 0, stream>>>(hist1, nb1, bs1);
    scan_row_kernel<<<NBINS, 256, 0, stream>>>(hist2, nb2, bs2);
    scan_row_kernel<<<1, 256, 0, stream>>>(bs1, NBINS, bs1 + NBINS);
    scan_row_kernel<<<1, 256, 0, stream>>>(bs2, NBINS, bs2 + NBINS);
    scatter_kernel<<<nb1, 256, 0, stream>>>(src1, dst1, E1, nb1, hist1, bs1, binned1);
    scatter_kernel<<<nb2, 256, 0, stream>>>(src2, dst2, E2, nb2, hist2, bs2, binned2);
    binfill_kernel<<<NBINS, 256, 0, stream>>>(binned1, bs1, rowptr1, dinv1, col1, E1);
    binfill_kernel<<<NBINS, 256, 0, stream>>>(binned2, bs2, rowptr2, dinv2, col2, E2);

    convW_kernel<<<DIM, 256, 0, stream>>>(W1, W2, Wt2);
    convW3_kernel<<<32, 256, 0, stream>>>(W3, Wt3);
    gemm12_mfma_kernel<<<(NNODES + 63) / 64, 256, 0, stream>>>(x, Wt2, dinv1, dinv2, hs8);
    agg12_kernel<<<(AGG_WAVES_G1 + AGG_WAVES_G2) / 4, 256, 0, stream>>>(
        hs8, rowptr1, col1, rowptr2, col2, dinv1, dinv2, b1, b2, E1, E2, hcat);
    gemm3_mfma_kernel<<<(NNODES + 255) / 256, 256, 0, stream>>>(hcat, Wt3, dinv1, gs);
    agg3_kernel<<<A3_WAVES / 4, 256, 0, stream>>>(gs, rowptr1, col1, dinv1, b3, out, E1);
}